// Round 3
// baseline (450.782 us; speedup 1.0000x reference)
//
#include <hip/hip_runtime.h>
#include <stdint.h>

typedef __bf16 bf16x8 __attribute__((ext_vector_type(8)));
typedef float floatx4 __attribute__((ext_vector_type(4)));
typedef unsigned short u16;
typedef u16 u16x8 __attribute__((ext_vector_type(8)));

__device__ __forceinline__ float bf2f(u16 u) {
    union { uint32_t i; float f; } v; v.i = ((uint32_t)u) << 16; return v.f;
}
__device__ __forceinline__ u16 f2bf(float f) {
    union { float f; uint32_t i; } v; v.f = f;
    uint32_t r = v.i + 0x7fffu + ((v.i >> 16) & 1u);
    return (u16)(r >> 16);
}

// async global->LDS, 16B per lane. LDS dest must be wave-uniform base; HW adds lane*16.
__device__ __forceinline__ void gload_lds16(const u16* g, u16* l) {
    __builtin_amdgcn_global_load_lds(
        (const __attribute__((address_space(1))) void*)g,
        (__attribute__((address_space(3))) void*)l,
        16, 0, 0);
}

#define TM 128
#define TN 128
#define BK 64
#define BUFSZ 16384   // u16 per double-buffer slot: A 8192 + B 8192 (16KB+16KB bytes)
#define RSTR 132      // bf16 repack tile row stride (u16)
#define FSTR 132      // fp32 repack tile row stride (floats)

// C = A[M,K] @ Bt[N,K]^T + bias[N] (+ addsrc); A,Bt,addsrc bf16; bias fp32; fp32 accum.
// bstride: per-batch B offset (elements); batch = row0>>12 (4096 rows/batch). 0 = shared B.
// 2-phase double-buffered pipeline (T3 minimum): stage(next) issued before ds_read+MFMA(cur),
// one barrier per K-step; both-sides XOR swizzle (rule 21) for bank-conflict-free ds_read.
__global__ __launch_bounds__(256) void gemm_bt_kernel(
    const u16* __restrict__ A, int lda,
    const u16* __restrict__ Bt, long bstride,
    const float* __restrict__ bias,
    const u16* __restrict__ addsrc, int ldadd,
    u16* __restrict__ C16, float* __restrict__ C32, int ldc,
    int K)
{
    __shared__ __attribute__((aligned(16))) u16 lds[2 * BUFSZ];  // 64 KiB
    const int tid  = threadIdx.x;
    const int wave = tid >> 6;
    const int lane = tid & 63;
    const int quad = lane >> 4;
    const int l16  = lane & 15;
    const int wm = wave >> 1, wn = wave & 1;

    // XCD-aware chunked swizzle (all launches have nwg % 8 == 0)
    const int gx   = gridDim.x;
    const int nwg  = gx * gridDim.y;
    const int wgid = blockIdx.y * gx + blockIdx.x;
    const int cpx  = nwg >> 3;
    const int swz  = (wgid & 7) * cpx + (wgid >> 3);
    const int row0 = (swz / gx) * TM;
    const int col0 = (swz % gx) * TN;
    const int batch = row0 >> 12;

    floatx4 acc[4][4] = {};

    // staging chunk cc = wave*4+c covers rows [cc*8, cc*8+8); lane l -> row cc*8+(l>>3).
    // K-offset XOR-swizzled by row&7 so linear gload_lds dest + swizzled ds_read agree.
    const int rsub = lane >> 3;
    const int ksub = ((lane & 7) ^ rsub) << 3;
    const u16* aptr[4]; const u16* bptr[4];
    const u16* Bb = Bt + (size_t)batch * bstride;
#pragma unroll
    for (int c = 0; c < 4; ++c) {
        const int cc = wave * 4 + c;
        aptr[c] = A  + (size_t)(row0 + cc * 8 + rsub) * lda + ksub;
        bptr[c] = Bb + (size_t)(col0 + cc * 8 + rsub) * K   + ksub;
    }

    const int NT = K / BK;
    // prologue: stage tile 0 into buffer 0
    {
        u16* sA = &lds[0]; u16* sB = &lds[8192];
#pragma unroll
        for (int c = 0; c < 4; ++c) {
            const int cc = wave * 4 + c;
            gload_lds16(aptr[c], &sA[cc * 512]);
            gload_lds16(bptr[c], &sB[cc * 512]);
        }
    }
    int cur = 0;
    for (int t = 0; t < NT; ++t) {
        __syncthreads();   // drains vmcnt(0): buf[cur] staged; prev ds_reads done
        if (t + 1 < NT) {  // issue next tile into other buffer; overlaps MFMA below
            u16* sA = &lds[(cur ^ 1) * BUFSZ]; u16* sB = sA + 8192;
            const int kt = (t + 1) * BK;
#pragma unroll
            for (int c = 0; c < 4; ++c) {
                const int cc = wave * 4 + c;
                gload_lds16(aptr[c] + kt, &sA[cc * 512]);
                gload_lds16(bptr[c] + kt, &sB[cc * 512]);
            }
        }
        u16* sA = &lds[cur * BUFSZ]; u16* sB = sA + 8192;
#pragma unroll
        for (int ks = 0; ks < 2; ++ks) {
            const int cidx = ks * 4 + quad;
            const int pgo = ((cidx ^ (l16 & 7)) << 3);
            bf16x8 af[4], bfr[4];
#pragma unroll
            for (int i = 0; i < 4; ++i) {
                int m = wm * 64 + i * 16 + l16;
                af[i] = *(const bf16x8*)&sA[m * BK + pgo];
            }
#pragma unroll
            for (int j = 0; j < 4; ++j) {
                int n = wn * 64 + j * 16 + l16;
                bfr[j] = *(const bf16x8*)&sB[n * BK + pgo];
            }
#pragma unroll
            for (int i = 0; i < 4; ++i)
#pragma unroll
                for (int j = 0; j < 4; ++j)
                    acc[i][j] = __builtin_amdgcn_mfma_f32_16x16x32_bf16(af[i], bfr[j], acc[i][j], 0, 0, 0);
        }
        cur ^= 1;
    }

    // epilogue. C/D layout: col=lane&15, row=quad*4+reg.
    if (C16) {
        __syncthreads();  // all ds_reads done before aliasing staging LDS
#pragma unroll
        for (int j = 0; j < 4; ++j) {
            int col = col0 + wn * 64 + j * 16 + l16;
            float bv = bias[col];
            int tcol = wn * 64 + j * 16 + l16;
#pragma unroll
            for (int i = 0; i < 4; ++i) {
                int trow = wm * 64 + i * 16 + quad * 4;
                int rowb = row0 + trow;
#pragma unroll
                for (int t = 0; t < 4; ++t) {
                    float v = acc[i][j][t] + bv;
                    if (addsrc) v += bf2f(addsrc[(size_t)(rowb + t) * ldadd + col]);
                    lds[(trow + t) * RSTR + tcol] = f2bf(v);
                }
            }
        }
        __syncthreads();
#pragma unroll
        for (int c = 0; c < 8; ++c) {
            int r  = c * 16 + (tid >> 4);
            int cu = (tid & 15) * 8;
            ushort4 lo = *(const ushort4*)&lds[r * RSTR + cu];
            ushort4 hi = *(const ushort4*)&lds[r * RSTR + cu + 4];
            u16x8 o;
            o[0] = lo.x; o[1] = lo.y; o[2] = lo.z; o[3] = lo.w;
            o[4] = hi.x; o[5] = hi.y; o[6] = hi.z; o[7] = hi.w;
            *(u16x8*)&C16[(size_t)(row0 + r) * ldc + col0 + cu] = o;
        }
    } else {
        // fp32 path: 2-pass LDS repack (64x132 fp32 tile = 33792B), dense dwordx4 stores
        float* ftile = (float*)lds;
#pragma unroll
        for (int pass = 0; pass < 2; ++pass) {
            __syncthreads();
            if (wm == pass) {
#pragma unroll
                for (int j = 0; j < 4; ++j) {
                    int tcol = wn * 64 + j * 16 + l16;
                    float bv = bias[col0 + tcol];
#pragma unroll
                    for (int i = 0; i < 4; ++i) {
                        int trow = i * 16 + quad * 4;  // 0..63 within half
#pragma unroll
                        for (int t = 0; t < 4; ++t)
                            ftile[(trow + t) * FSTR + tcol] = acc[i][j][t] + bv;
                    }
                }
            }
            __syncthreads();
#pragma unroll
            for (int c = 0; c < 8; ++c) {
                int r  = c * 8 + (tid >> 5);
                int cu = (tid & 31) * 4;
                float4 v = *(const float4*)&ftile[r * FSTR + cu];
                *(float4*)&C32[(size_t)(row0 + pass * 64 + r) * ldc + col0 + cu] = v;
            }
        }
    }
}

// Barrier-free: one wave per row of QK[M,1024]; lane covers 8 u16 of Q and 8 of K.
// l2-normalize Q,K halves; accumulate g[b,:] += Qn (fp32, pre-round); 8 rows/wave.
__global__ __launch_bounds__(256) void norm_g_kernel(u16* __restrict__ QK, float* __restrict__ g)
{
    const int tid  = threadIdx.x;
    const int wave = tid >> 6, lane = tid & 63;
    const int gw   = blockIdx.x * 4 + wave;    // 4096 waves, 8 rows each
    const int row0 = gw * 8;
    const int batch = row0 >> 12;              // 8 rows never straddle a 4096 boundary
    float gacc[8] = {0.f};
    for (int rr = 0; rr < 8; ++rr) {
        const size_t rb = (size_t)(row0 + rr) * 1024 + lane * 8;
        u16x8 q = *(const u16x8*)(QK + rb);
        u16x8 k = *(const u16x8*)(QK + rb + 512);
        float qf[8], kf[8];
        float ssq = 0.f, ssk = 0.f;
#pragma unroll
        for (int i = 0; i < 8; ++i) {
            qf[i] = bf2f(q[i]); kf[i] = bf2f(k[i]);
            ssq += qf[i] * qf[i]; ssk += kf[i] * kf[i];
        }
#pragma unroll
        for (int off = 32; off > 0; off >>= 1) {
            ssq += __shfl_xor(ssq, off);
            ssk += __shfl_xor(ssk, off);
        }
        float rsq = rsqrtf(fmaxf(ssq, 1e-12f));
        float rsk = rsqrtf(fmaxf(ssk, 1e-12f));
        u16x8 qo, ko;
#pragma unroll
        for (int i = 0; i < 8; ++i) {
            float qn = qf[i] * rsq;
            qo[i] = f2bf(qn);
            ko[i] = f2bf(kf[i] * rsk);
            gacc[i] += qn;
        }
        *(u16x8*)(QK + rb)       = qo;
        *(u16x8*)(QK + rb + 512) = ko;
    }
    float* gb = g + batch * 512 + lane * 8;
#pragma unroll
    for (int i = 0; i < 8; ++i) atomicAdd(&gb[i], gacc[i]);
}

// BtP8[b][n][k] = bf16(g[b][k] * wp[k][n])  — folds the Kn*g scaling into per-batch weights.
__global__ __launch_bounds__(256) void scale_wp_kernel(const float* __restrict__ wp,
                                                       const float* __restrict__ g,
                                                       u16* __restrict__ BtP8)
{
    __shared__ u16 tile[32][34];
    const int b   = blockIdx.x >> 8;
    const int bid = blockIdx.x & 255;
    const int tk = bid & 15;
    const int tn = bid >> 4;
    const int c  = threadIdx.x & 31;
    const int r0 = threadIdx.x >> 5;
    const float* gb = g + b * 512;
#pragma unroll
    for (int i = 0; i < 4; ++i) {
        int r = r0 + i * 8;
        int k = tk * 32 + r;
        tile[r][c] = f2bf(gb[k] * wp[(size_t)k * 512 + tn * 32 + c]);
    }
    __syncthreads();
    u16* Bt = BtP8 + (size_t)b * 512 * 512;
#pragma unroll
    for (int i = 0; i < 4; ++i) {
        int r = r0 + i * 8;
        Bt[(size_t)(tn * 32 + r) * 512 + tk * 32 + c] = tile[c][r];
    }
}

// x (fp32) -> bf16
__global__ __launch_bounds__(256) void convert_x_kernel(const float* __restrict__ x, u16* __restrict__ xb)
{
    size_t i = ((size_t)blockIdx.x * 256 + threadIdx.x) * 4;
    float4 v = *(const float4*)(x + i);
    ushort4 o;
    o.x = f2bf(v.x); o.y = f2bf(v.y); o.z = f2bf(v.z); o.w = f2bf(v.w);
    *(ushort4*)(xb + i) = o;
}

// LDS-tiled transpose of three 512x512 fp32 weights (wq, wk, wf) -> bf16 B^T layout.
__global__ __launch_bounds__(256) void transpose3_kernel(
    const float* __restrict__ w0, const float* __restrict__ w1, const float* __restrict__ w2,
    u16* __restrict__ d0, u16* __restrict__ d1, u16* __restrict__ d2)
{
    __shared__ u16 tile[32][34];
    const int which = blockIdx.x >> 8;
    const float* W = (which == 0) ? w0 : (which == 1) ? w1 : w2;
    u16* Bt = (which == 0) ? d0 : (which == 1) ? d1 : d2;
    const int bid = blockIdx.x & 255;
    const int tk = bid & 15;
    const int tn = bid >> 4;
    const int c  = threadIdx.x & 31;
    const int r0 = threadIdx.x >> 5;
#pragma unroll
    for (int i = 0; i < 4; ++i) {
        int r = r0 + i * 8;
        tile[r][c] = f2bf(W[(size_t)(tk * 32 + r) * 512 + tn * 32 + c]);
    }
    __syncthreads();
#pragma unroll
    for (int i = 0; i < 4; ++i) {
        int r = r0 + i * 8;
        Bt[(size_t)(tn * 32 + r) * 512 + tk * 32 + c] = tile[c][r];
    }
}

__global__ __launch_bounds__(256) void bias_cat_kernel(const float* __restrict__ bq, const float* __restrict__ bk,
                                                       float* __restrict__ b)
{
    int id = blockIdx.x * 256 + threadIdx.x; // 0..1023
    b[id] = (id < 512) ? bq[id] : bk[id - 512];
}

extern "C" void kernel_launch(void* const* d_in, const int* in_sizes, int n_in,
                              void* d_out, int out_size, void* d_ws, size_t ws_size,
                              hipStream_t stream)
{
    const float* x  = (const float*)d_in[0];
    const float* wq = (const float*)d_in[1];
    const float* bq = (const float*)d_in[2];
    const float* wk = (const float*)d_in[3];
    const float* bk = (const float*)d_in[4];
    const float* wp = (const float*)d_in[5];
    const float* bp = (const float*)d_in[6];
    const float* wf = (const float*)d_in[7];
    const float* bf = (const float*)d_in[8];
    // d_in[9] = w_g unused: softmax over a size-1 axis is identically 1.

    char* ws = (char*)d_ws;
    u16*   xb     = (u16*)(ws);                 // 32768 x 512 bf16 = 32 MiB
    u16*   T      = (u16*)(ws);                 // alias: xb dead after GEMM1
    u16*   QK     = (u16*)(ws + 33554432);      // 32768 x 1024 bf16 = 64 MiB
    u16*   Bt1    = (u16*)(ws + 100663296);     // 1024 x 512 bf16 = 1 MiB
    u16*   BtP8   = (u16*)(ws + 101711872);     // 8 x 512 x 512 bf16 = 4 MiB
    u16*   BtF    = (u16*)(ws + 105906176);     // 512 x 512 bf16
    float* biasQK = (float*)(ws + 106430464);   // 1024 fp32
    float* g      = (float*)(ws + 106434560);   // 8 x 512 fp32

    hipMemsetAsync(g, 0, 8 * 512 * sizeof(float), stream);
    convert_x_kernel<<<16384, 256, 0, stream>>>(x, xb);
    bias_cat_kernel<<<4, 256, 0, stream>>>(bq, bk, biasQK);
    transpose3_kernel<<<768, 256, 0, stream>>>(wq, wk, wf, Bt1, Bt1 + 512 * 512, BtF);

    // QK = x @ [wq|wk] + [bq|bk]          (bf16 out)   nwg = 2048
    gemm_bt_kernel<<<dim3(8, 256), 256, 0, stream>>>(xb, 512, Bt1, 0, biasQK, nullptr, 0, QK, nullptr, 1024, 512);
    // normalize Q,K halves in place; g[b] = sum_rows Qn
    norm_g_kernel<<<1024, 256, 0, stream>>>(QK, g);
    // fold g into per-batch wp:  BtP8[b] = (diag(g[b]) @ wp)^T
    scale_wp_kernel<<<2048, 256, 0, stream>>>(wp, g, BtP8);
    // T = Kn @ (g*wp) + bp + Qn           (bf16 out)   nwg = 1024, per-batch B
    gemm_bt_kernel<<<dim3(4, 256), 256, 0, stream>>>(QK + 512, 1024, BtP8, 512 * 512, bp, QK, 1024, T, nullptr, 512, 512);
    // out = T @ wf + bf                   (fp32 out)   nwg = 1024
    gemm_bt_kernel<<<dim3(4, 256), 256, 0, stream>>>(T, 512, BtF, 0, bf, nullptr, 0, nullptr, (float*)d_out, 512, 512);
}

// Round 4
// 304.677 us; speedup vs baseline: 1.4795x; 1.4795x over previous
//
#include <hip/hip_runtime.h>
#include <stdint.h>

typedef __bf16 bf16x8 __attribute__((ext_vector_type(8)));
typedef float floatx4 __attribute__((ext_vector_type(4)));
typedef unsigned short u16;
typedef u16 u16x8 __attribute__((ext_vector_type(8)));

__device__ __forceinline__ float bf2f(u16 u) {
    union { uint32_t i; float f; } v; v.i = ((uint32_t)u) << 16; return v.f;
}
__device__ __forceinline__ u16 f2bf(float f) {
    union { float f; uint32_t i; } v; v.f = f;
    uint32_t r = v.i + 0x7fffu + ((v.i >> 16) & 1u);
    return (u16)(r >> 16);
}

// async global->LDS, 16B per lane. LDS dest must be wave-uniform base; HW adds lane*16.
__device__ __forceinline__ void gload_lds16(const u16* g, u16* l) {
    __builtin_amdgcn_global_load_lds(
        (const __attribute__((address_space(1))) void*)g,
        (__attribute__((address_space(3))) void*)l,
        16, 0, 0);
}

#define TM 128
#define TN 128
#define BK 64
#define RSTR 132      // bf16 repack tile row stride (u16); LDS = 128*132*2 = 33792 B (4 blocks/CU)
#define FSTR 132      // fp32 repack tile row stride (floats); 64*132*4 = 33792 B

// C = A[M,K] @ Bt[N,K]^T + bias[N] (+ scaled addsrc); A,Bt,addsrc bf16; fp32 accum.
// bstride: per-batch B offset (elements); batch = row0>>12. 0 = shared B.
// ssq_row: if set, acc *= rsqrt(max(ssq_row[row],1e-12))  (folded row-normalization)
// ssq_add: if set, addsrc term *= rsqrt(max(ssq_add[row],1e-12))
// ssq_out: if set (bf16 path), atomicAdd per-row sum-of-squares of the bf16 OUTPUT into
//          ssq_out[(col0>>9)*Mtot + row]  (GEMM1: Q half cols<512, K half cols>=512).
// Single-buffer m97 structure (33792B LDS, proven 61.7us) + both-sides XOR swizzle (rule 21).
__global__ __launch_bounds__(256) void gemm_bt_kernel(
    const u16* __restrict__ A, int lda,
    const u16* __restrict__ Bt, long bstride,
    const float* __restrict__ bias,
    const u16* __restrict__ addsrc, int ldadd,
    const float* __restrict__ ssq_add,
    const float* __restrict__ ssq_row,
    float* __restrict__ ssq_out,
    u16* __restrict__ C16, float* __restrict__ C32, int ldc,
    int K)
{
    __shared__ __attribute__((aligned(16))) u16 lds[TM * RSTR];  // 33792 B
    u16* lsA = lds;
    u16* lsB = lds + TM * BK;
    const int tid  = threadIdx.x;
    const int wave = tid >> 6;
    const int lane = tid & 63;
    const int quad = lane >> 4;
    const int l16  = lane & 15;
    const int wm = wave >> 1, wn = wave & 1;

    // XCD-aware chunked swizzle (all launches have nwg % 8 == 0)
    const int gx   = gridDim.x;
    const int nwg  = gx * gridDim.y;
    const int wgid = blockIdx.y * gx + blockIdx.x;
    const int cpx  = nwg >> 3;
    const int swz  = (wgid & 7) * cpx + (wgid >> 3);
    const int row0 = (swz / gx) * TM;
    const int col0 = (swz % gx) * TN;
    const int batch = row0 >> 12;
    const int Mtot  = gridDim.y * TM;

    floatx4 acc[4][4] = {};

    // staging chunk cc = wave*4+c covers rows [cc*8, cc*8+8); lane l -> row cc*8+(l>>3).
    // K-offset XOR-swizzled by row&7 so linear gload_lds dest + swizzled ds_read agree.
    const int rsub = lane >> 3;
    const int ksub = ((lane & 7) ^ rsub) << 3;
    const u16* aptr[4]; const u16* bptr[4];
    const u16* Bb = Bt + (size_t)batch * bstride;
#pragma unroll
    for (int c = 0; c < 4; ++c) {
        const int cc = wave * 4 + c;
        aptr[c] = A  + (size_t)(row0 + cc * 8 + rsub) * lda + ksub;
        bptr[c] = Bb + (size_t)(col0 + cc * 8 + rsub) * K   + ksub;
    }

    for (int kt = 0; kt < K; kt += BK) {
#pragma unroll
        for (int c = 0; c < 4; ++c) {
            const int cc = wave * 4 + c;
            gload_lds16(aptr[c] + kt, &lsA[cc * 512]);
            gload_lds16(bptr[c] + kt, &lsB[cc * 512]);
        }
        __syncthreads();
#pragma unroll
        for (int ks = 0; ks < 2; ++ks) {
            const int cidx = ks * 4 + quad;
            const int pgo = ((cidx ^ (l16 & 7)) << 3);
            bf16x8 af[4], bfr[4];
#pragma unroll
            for (int i = 0; i < 4; ++i) {
                int m = wm * 64 + i * 16 + l16;
                af[i] = *(const bf16x8*)&lsA[m * BK + pgo];
            }
#pragma unroll
            for (int j = 0; j < 4; ++j) {
                int n = wn * 64 + j * 16 + l16;
                bfr[j] = *(const bf16x8*)&lsB[n * BK + pgo];
            }
#pragma unroll
            for (int i = 0; i < 4; ++i)
#pragma unroll
                for (int j = 0; j < 4; ++j)
                    acc[i][j] = __builtin_amdgcn_mfma_f32_16x16x32_bf16(af[i], bfr[j], acc[i][j], 0, 0, 0);
        }
        __syncthreads();
    }

    // epilogue. C/D layout: col=lane&15, row=quad*4+reg.
    if (C16) {
        // per-row normalization scales (folded l2-norm), hoisted out of the j-loop
        float rsr[16], rsa[16];
        if (ssq_row || ssq_add) {
#pragma unroll
            for (int i = 0; i < 4; ++i)
#pragma unroll
                for (int t = 0; t < 4; ++t) {
                    int rowb = row0 + wm * 64 + i * 16 + quad * 4 + t;
                    if (ssq_row) rsr[i * 4 + t] = rsqrtf(fmaxf(ssq_row[rowb], 1e-12f));
                    if (ssq_add) rsa[i * 4 + t] = rsqrtf(fmaxf(ssq_add[rowb], 1e-12f));
                }
        }
#pragma unroll
        for (int j = 0; j < 4; ++j) {
            int col = col0 + wn * 64 + j * 16 + l16;
            float bv = bias[col];
            int tcol = wn * 64 + j * 16 + l16;
#pragma unroll
            for (int i = 0; i < 4; ++i) {
                int trow = wm * 64 + i * 16 + quad * 4;
                int rowb = row0 + trow;
#pragma unroll
                for (int t = 0; t < 4; ++t) {
                    float v = acc[i][j][t];
                    if (ssq_row) v *= rsr[i * 4 + t];
                    v += bv;
                    if (addsrc) {
                        float a = bf2f(addsrc[(size_t)(rowb + t) * ldadd + col]);
                        if (ssq_add) a *= rsa[i * 4 + t];
                        v += a;
                    }
                    lds[(trow + t) * RSTR + tcol] = f2bf(v);
                }
            }
        }
        __syncthreads();
        float* so = ssq_out ? (ssq_out + (size_t)(col0 >> 9) * Mtot + row0) : nullptr;
#pragma unroll
        for (int c = 0; c < 8; ++c) {
            int r  = c * 16 + (tid >> 4);
            int cu = (tid & 15) * 8;
            ushort4 lo = *(const ushort4*)&lds[r * RSTR + cu];
            ushort4 hi = *(const ushort4*)&lds[r * RSTR + cu + 4];
            u16x8 o;
            o[0] = lo.x; o[1] = lo.y; o[2] = lo.z; o[3] = lo.w;
            o[4] = hi.x; o[5] = hi.y; o[6] = hi.z; o[7] = hi.w;
            *(u16x8*)&C16[(size_t)(row0 + r) * ldc + col0 + cu] = o;
            if (so) {
                // per-row sum of squares of the rounded output (matches prior norm numerics);
                // 16 lanes (same l16 group) share row r and cover 128 cols of this block.
                float ss = 0.f;
#pragma unroll
                for (int q2 = 0; q2 < 8; ++q2) { float f = bf2f(o[q2]); ss += f * f; }
                ss += __shfl_xor(ss, 1);
                ss += __shfl_xor(ss, 2);
                ss += __shfl_xor(ss, 4);
                ss += __shfl_xor(ss, 8);
                if ((lane & 15) == 0) atomicAdd(&so[r], ss);
            }
        }
    } else {
        // fp32 path: 2-pass LDS repack (64x132 fp32 tile), dense dwordx4 stores
        float* ftile = (float*)lds;
#pragma unroll
        for (int pass = 0; pass < 2; ++pass) {
            __syncthreads();
            if (wm == pass) {
#pragma unroll
                for (int j = 0; j < 4; ++j) {
                    int tcol = wn * 64 + j * 16 + l16;
                    float bv = bias[col0 + tcol];
#pragma unroll
                    for (int i = 0; i < 4; ++i) {
                        int trow = i * 16 + quad * 4;
#pragma unroll
                        for (int t = 0; t < 4; ++t)
                            ftile[(trow + t) * FSTR + tcol] = acc[i][j][t] + bv;
                    }
                }
            }
            __syncthreads();
#pragma unroll
            for (int c = 0; c < 8; ++c) {
                int r  = c * 8 + (tid >> 5);
                int cu = (tid & 31) * 4;
                float4 v = *(const float4*)&ftile[r * FSTR + cu];
                *(float4*)&C32[(size_t)(row0 + pass * 64 + r) * ldc + col0 + cu] = v;
            }
        }
    }
}

// g[b,:] += sum_rows rsqrt(ssqQ[row]) * Q[row,:]   (Q = cols 0..511 of QK, raw bf16)
// 256 blocks x 128 rows; 4 waves x 32 rows; independent loads (no dependency chain);
// block-level LDS reduce -> 512 atomics/block.
__global__ __launch_bounds__(256) void gsum_kernel(const u16* __restrict__ QK,
                                                   const float* __restrict__ ssqQ,
                                                   float* __restrict__ g)
{
    __shared__ float gtile[4][512];
    const int lane = threadIdx.x & 63;
    const int wave = threadIdx.x >> 6;
    const int row0 = blockIdx.x * 128 + wave * 32;
    const int batch = row0 >> 12;   // 128 | 4096: block never straddles a batch
    const int d = lane * 8;
    float gacc[8] = {};
    for (int rr = 0; rr < 32; ++rr) {
        int row = row0 + rr;
        float s = rsqrtf(fmaxf(ssqQ[row], 1e-12f));
        u16x8 q = *(const u16x8*)(QK + (size_t)row * 1024 + d);
#pragma unroll
        for (int i = 0; i < 8; ++i) gacc[i] += s * bf2f(q[i]);
    }
#pragma unroll
    for (int i = 0; i < 8; ++i) gtile[wave][d + i] = gacc[i];
    __syncthreads();
    int c2 = threadIdx.x * 2;
    float s0 = gtile[0][c2]     + gtile[1][c2]     + gtile[2][c2]     + gtile[3][c2];
    float s1 = gtile[0][c2 + 1] + gtile[1][c2 + 1] + gtile[2][c2 + 1] + gtile[3][c2 + 1];
    atomicAdd(&g[batch * 512 + c2], s0);
    atomicAdd(&g[batch * 512 + c2 + 1], s1);
}

// BtP8[b][n][k] = bf16(g[b][k] * wp[k][n])  — folds the g scaling into per-batch weights.
__global__ __launch_bounds__(256) void scale_wp_kernel(const float* __restrict__ wp,
                                                       const float* __restrict__ g,
                                                       u16* __restrict__ BtP8)
{
    __shared__ u16 tile[32][34];
    const int b   = blockIdx.x >> 8;
    const int bid = blockIdx.x & 255;
    const int tk = bid & 15;
    const int tn = bid >> 4;
    const int c  = threadIdx.x & 31;
    const int r0 = threadIdx.x >> 5;
    const float* gb = g + b * 512;
#pragma unroll
    for (int i = 0; i < 4; ++i) {
        int r = r0 + i * 8;
        int k = tk * 32 + r;
        tile[r][c] = f2bf(gb[k] * wp[(size_t)k * 512 + tn * 32 + c]);
    }
    __syncthreads();
    u16* Bt = BtP8 + (size_t)b * 512 * 512;
#pragma unroll
    for (int i = 0; i < 4; ++i) {
        int r = r0 + i * 8;
        Bt[(size_t)(tn * 32 + r) * 512 + tk * 32 + c] = tile[c][r];
    }
}

// x (fp32) -> bf16
__global__ __launch_bounds__(256) void convert_x_kernel(const float* __restrict__ x, u16* __restrict__ xb)
{
    size_t i = ((size_t)blockIdx.x * 256 + threadIdx.x) * 4;
    float4 v = *(const float4*)(x + i);
    ushort4 o;
    o.x = f2bf(v.x); o.y = f2bf(v.y); o.z = f2bf(v.z); o.w = f2bf(v.w);
    *(ushort4*)(xb + i) = o;
}

// LDS-tiled transpose of three 512x512 fp32 weights (wq, wk, wf) -> bf16 B^T layout.
__global__ __launch_bounds__(256) void transpose3_kernel(
    const float* __restrict__ w0, const float* __restrict__ w1, const float* __restrict__ w2,
    u16* __restrict__ d0, u16* __restrict__ d1, u16* __restrict__ d2)
{
    __shared__ u16 tile[32][34];
    const int which = blockIdx.x >> 8;
    const float* W = (which == 0) ? w0 : (which == 1) ? w1 : w2;
    u16* Bt = (which == 0) ? d0 : (which == 1) ? d1 : d2;
    const int bid = blockIdx.x & 255;
    const int tk = bid & 15;
    const int tn = bid >> 4;
    const int c  = threadIdx.x & 31;
    const int r0 = threadIdx.x >> 5;
#pragma unroll
    for (int i = 0; i < 4; ++i) {
        int r = r0 + i * 8;
        tile[r][c] = f2bf(W[(size_t)(tk * 32 + r) * 512 + tn * 32 + c]);
    }
    __syncthreads();
#pragma unroll
    for (int i = 0; i < 4; ++i) {
        int r = r0 + i * 8;
        Bt[(size_t)(tn * 32 + r) * 512 + tk * 32 + c] = tile[c][r];
    }
}

__global__ __launch_bounds__(256) void bias_cat_kernel(const float* __restrict__ bq, const float* __restrict__ bk,
                                                       float* __restrict__ b)
{
    int id = blockIdx.x * 256 + threadIdx.x; // 0..1023
    b[id] = (id < 512) ? bq[id] : bk[id - 512];
}

extern "C" void kernel_launch(void* const* d_in, const int* in_sizes, int n_in,
                              void* d_out, int out_size, void* d_ws, size_t ws_size,
                              hipStream_t stream)
{
    const float* x  = (const float*)d_in[0];
    const float* wq = (const float*)d_in[1];
    const float* bq = (const float*)d_in[2];
    const float* wk = (const float*)d_in[3];
    const float* bk = (const float*)d_in[4];
    const float* wp = (const float*)d_in[5];
    const float* bp = (const float*)d_in[6];
    const float* wf = (const float*)d_in[7];
    const float* bf = (const float*)d_in[8];
    // d_in[9] = w_g unused: softmax over a size-1 axis is identically 1.

    char* ws = (char*)d_ws;
    u16*   xb     = (u16*)(ws);                 // 32768 x 512 bf16 = 32 MiB
    u16*   T      = (u16*)(ws);                 // alias: xb dead after GEMM1
    u16*   QK     = (u16*)(ws + 33554432);      // 32768 x 1024 bf16 = 64 MiB
    u16*   Bt1    = (u16*)(ws + 100663296);     // 1024 x 512 bf16 = 1 MiB
    u16*   BtP8   = (u16*)(ws + 101711872);     // 8 x 512 x 512 bf16 = 4 MiB
    u16*   BtF    = (u16*)(ws + 105906176);     // 512 x 512 bf16
    float* biasQK = (float*)(ws + 106430464);   // 1024 fp32
    float* g      = (float*)(ws + 106434560);   // 8 x 512 fp32 = 16 KiB
    float* ssq    = (float*)(ws + 106450944);   // 2 x 32768 fp32 = 256 KiB (Q norms, K norms)

    hipMemsetAsync(g, 0, 8 * 512 * sizeof(float), stream);
    hipMemsetAsync(ssq, 0, 2 * 32768 * sizeof(float), stream);
    convert_x_kernel<<<16384, 256, 0, stream>>>(x, xb);
    bias_cat_kernel<<<4, 256, 0, stream>>>(bq, bk, biasQK);
    transpose3_kernel<<<768, 256, 0, stream>>>(wq, wk, wf, Bt1, Bt1 + 512 * 512, BtF);

    // QK = x @ [wq|wk] + [bq|bk]  (bf16 out) + per-row ssq of Q,K halves     nwg = 2048
    gemm_bt_kernel<<<dim3(8, 256), 256, 0, stream>>>(
        xb, 512, Bt1, 0, biasQK, nullptr, 0, nullptr, nullptr, ssq, QK, nullptr, 1024, 512);
    // g[b,:] = sum_rows Qn = sum_rows rsqrt(ssqQ[r]) * Q[r,:]
    gsum_kernel<<<256, 256, 0, stream>>>(QK, ssq, g);
    // fold g into per-batch wp:  BtP8[b] = (diag(g[b]) @ wp)^T
    scale_wp_kernel<<<2048, 256, 0, stream>>>(wp, g, BtP8);
    // T = rsk[row]*(Kraw @ (g*wp)) + bp + rsq[row]*Qraw   (bf16 out)         nwg = 1024
    gemm_bt_kernel<<<dim3(4, 256), 256, 0, stream>>>(
        QK + 512, 1024, BtP8, 512 * 512, bp, QK, 1024, ssq, ssq + 32768, nullptr, T, nullptr, 512, 512);
    // out = T @ wf + bf   (fp32 out)                                         nwg = 1024
    gemm_bt_kernel<<<dim3(4, 256), 256, 0, stream>>>(
        T, 512, BtF, 0, bf, nullptr, 0, nullptr, nullptr, nullptr, nullptr, (float*)d_out, 512, 512);
}

// Round 5
// 261.522 us; speedup vs baseline: 1.7237x; 1.1650x over previous
//
#include <hip/hip_runtime.h>
#include <stdint.h>

typedef __bf16 bf16x8 __attribute__((ext_vector_type(8)));
typedef float floatx4 __attribute__((ext_vector_type(4)));
typedef unsigned short u16;
typedef u16 u16x8 __attribute__((ext_vector_type(8)));

__device__ __forceinline__ float bf2f(u16 u) {
    union { uint32_t i; float f; } v; v.i = ((uint32_t)u) << 16; return v.f;
}
__device__ __forceinline__ u16 f2bf(float f) {
    union { float f; uint32_t i; } v; v.f = f;
    uint32_t r = v.i + 0x7fffu + ((v.i >> 16) & 1u);
    return (u16)(r >> 16);
}

// async global->LDS, 16B per lane. LDS dest must be wave-uniform base; HW adds lane*16.
__device__ __forceinline__ void gload_lds16(const u16* g, u16* l) {
    __builtin_amdgcn_global_load_lds(
        (const __attribute__((address_space(1))) void*)g,
        (__attribute__((address_space(3))) void*)l,
        16, 0, 0);
}

#define TM 128
#define TN 128
#define BK 64
#define RSTR 132      // bf16 repack tile row stride (u16); LDS = 128*132*2 = 33792 B (4 blocks/CU)
#define FSTR 132      // fp32 repack tile row stride (floats); 64*132*4 = 33792 B

// C = A[M,K] @ Bt[N,K]^T + bias[N]; A,Bt bf16; fp32 accum.
// EPI=0: bf16 out + per-row output sum-of-squares -> ssq_out[(col0>>9)*Mtot + row] (GEMM1)
// EPI=1: bf16 out, acc *= rsqrt(ssq_row[row]), += rsqrt(ssq_add[row])*addsrc     (GEMM2)
// EPI=2: fp32 out, plain bias                                                     (GEMM3)
// Single-buffer m97 structure (proven R2: 61.7us) + both-sides XOR swizzle (rule 21)
// + XCD-aware chunked blockIdx swizzle (nwg % 8 == 0 on all launches).
template<int EPI>
__global__ __launch_bounds__(256) void gemm_bt(
    const u16* __restrict__ A, int lda,
    const u16* __restrict__ Bt, long bstride,
    const float* __restrict__ bias,
    const u16* __restrict__ addsrc, int ldadd,
    const float* __restrict__ ssq_add,
    const float* __restrict__ ssq_row,
    float* __restrict__ ssq_out,
    u16* __restrict__ C16, float* __restrict__ C32, int ldc,
    int K)
{
    __shared__ __attribute__((aligned(16))) u16 lds[TM * RSTR];  // 33792 B
    u16* lsA = lds;
    u16* lsB = lds + TM * BK;
    const int tid  = threadIdx.x;
    const int wave = tid >> 6;
    const int lane = tid & 63;
    const int quad = lane >> 4;
    const int l16  = lane & 15;
    const int wm = wave >> 1, wn = wave & 1;

    const int gx   = gridDim.x;
    const int nwg  = gx * gridDim.y;
    const int wgid = blockIdx.y * gx + blockIdx.x;
    const int cpx  = nwg >> 3;
    const int swz  = (wgid & 7) * cpx + (wgid >> 3);
    const int row0 = (swz / gx) * TM;
    const int col0 = (swz % gx) * TN;
    const int batch = row0 >> 12;
    const int Mtot  = gridDim.y * TM;

    floatx4 acc[4][4] = {};

    // staging chunk cc = wave*4+c covers rows [cc*8, cc*8+8); lane l -> row cc*8+(l>>3).
    // K-offset XOR-swizzled by row&7 so linear gload_lds dest + swizzled ds_read agree.
    const int rsub = lane >> 3;
    const int ksub = ((lane & 7) ^ rsub) << 3;
    const u16* aptr[4]; const u16* bptr[4];
    const u16* Bb = Bt + (size_t)batch * bstride;
#pragma unroll
    for (int c = 0; c < 4; ++c) {
        const int cc = wave * 4 + c;
        aptr[c] = A  + (size_t)(row0 + cc * 8 + rsub) * lda + ksub;
        bptr[c] = Bb + (size_t)(col0 + cc * 8 + rsub) * K   + ksub;
    }

    for (int kt = 0; kt < K; kt += BK) {
#pragma unroll
        for (int c = 0; c < 4; ++c) {
            const int cc = wave * 4 + c;
            gload_lds16(aptr[c] + kt, &lsA[cc * 512]);
            gload_lds16(bptr[c] + kt, &lsB[cc * 512]);
        }
        __syncthreads();
#pragma unroll
        for (int ks = 0; ks < 2; ++ks) {
            const int cidx = ks * 4 + quad;
            const int pgo = ((cidx ^ (l16 & 7)) << 3);
            bf16x8 af[4], bfr[4];
#pragma unroll
            for (int i = 0; i < 4; ++i) {
                int m = wm * 64 + i * 16 + l16;
                af[i] = *(const bf16x8*)&lsA[m * BK + pgo];
            }
#pragma unroll
            for (int j = 0; j < 4; ++j) {
                int n = wn * 64 + j * 16 + l16;
                bfr[j] = *(const bf16x8*)&lsB[n * BK + pgo];
            }
#pragma unroll
            for (int i = 0; i < 4; ++i)
#pragma unroll
                for (int j = 0; j < 4; ++j)
                    acc[i][j] = __builtin_amdgcn_mfma_f32_16x16x32_bf16(af[i], bfr[j], acc[i][j], 0, 0, 0);
        }
        __syncthreads();
    }

    // epilogue. C/D layout: col=lane&15, row=quad*4+reg (validated).
    if constexpr (EPI == 0 || EPI == 1) {
        float rsr[16], rsa[16];
        if constexpr (EPI == 1) {
#pragma unroll
            for (int i = 0; i < 4; ++i)
#pragma unroll
                for (int t = 0; t < 4; ++t) {
                    int rowb = row0 + wm * 64 + i * 16 + quad * 4 + t;
                    rsr[i * 4 + t] = rsqrtf(fmaxf(ssq_row[rowb], 1e-12f));
                    rsa[i * 4 + t] = rsqrtf(fmaxf(ssq_add[rowb], 1e-12f));
                }
        }
#pragma unroll
        for (int j = 0; j < 4; ++j) {
            int col = col0 + wn * 64 + j * 16 + l16;
            float bv = bias[col];
            int tcol = wn * 64 + j * 16 + l16;
#pragma unroll
            for (int i = 0; i < 4; ++i) {
                int trow = wm * 64 + i * 16 + quad * 4;
                int rowb = row0 + trow;
#pragma unroll
                for (int t = 0; t < 4; ++t) {
                    float v;
                    if constexpr (EPI == 1) {
                        v = acc[i][j][t] * rsr[i * 4 + t] + bv
                          + bf2f(addsrc[(size_t)(rowb + t) * ldadd + col]) * rsa[i * 4 + t];
                    } else {
                        v = acc[i][j][t] + bv;
                        (void)rowb;
                    }
                    lds[(trow + t) * RSTR + tcol] = f2bf(v);
                }
            }
        }
        __syncthreads();
        float ssl[8];
#pragma unroll
        for (int c = 0; c < 8; ++c) {
            int r  = c * 16 + (tid >> 4);
            int cu = (tid & 15) * 8;
            ushort4 lo = *(const ushort4*)&lds[r * RSTR + cu];
            ushort4 hi = *(const ushort4*)&lds[r * RSTR + cu + 4];
            u16x8 o;
            o[0] = lo.x; o[1] = lo.y; o[2] = lo.z; o[3] = lo.w;
            o[4] = hi.x; o[5] = hi.y; o[6] = hi.z; o[7] = hi.w;
            *(u16x8*)&C16[(size_t)(row0 + r) * ldc + col0 + cu] = o;
            if constexpr (EPI == 0) {
                float ss = 0.f;
#pragma unroll
                for (int q2 = 0; q2 < 8; ++q2) { float f = bf2f(o[q2]); ss += f * f; }
                ssl[c] = ss;
            }
        }
        if constexpr (EPI == 0) {
            // 8 independent shfl-reduce chains (interleaved by scheduler), then 8 atomics
            float* so = ssq_out + (size_t)(col0 >> 9) * Mtot + row0;
#pragma unroll
            for (int c = 0; c < 8; ++c) {
                float s = ssl[c];
                s += __shfl_xor(s, 1);
                s += __shfl_xor(s, 2);
                s += __shfl_xor(s, 4);
                s += __shfl_xor(s, 8);
                if ((lane & 15) == 0) atomicAdd(&so[c * 16 + (tid >> 4)], s);
            }
        }
    } else {
        // EPI=2: fp32 out, 2-pass LDS repack (64x132 fp32 tile), dense dwordx4 stores
        float* ftile = (float*)lds;
#pragma unroll
        for (int pass = 0; pass < 2; ++pass) {
            __syncthreads();
            if (wm == pass) {
#pragma unroll
                for (int j = 0; j < 4; ++j) {
                    int tcol = wn * 64 + j * 16 + l16;
                    float bv = bias[col0 + tcol];
#pragma unroll
                    for (int i = 0; i < 4; ++i) {
                        int trow = i * 16 + quad * 4;
#pragma unroll
                        for (int t = 0; t < 4; ++t)
                            ftile[(trow + t) * FSTR + tcol] = acc[i][j][t] + bv;
                    }
                }
            }
            __syncthreads();
#pragma unroll
            for (int c = 0; c < 8; ++c) {
                int r  = c * 8 + (tid >> 5);
                int cu = (tid & 31) * 4;
                float4 v = *(const float4*)&ftile[r * FSTR + cu];
                *(float4*)&C32[(size_t)(row0 + pass * 64 + r) * ldc + col0 + cu] = v;
            }
        }
    }
}

// g[b,:] += sum_rows rsqrt(ssqQ[row]) * Q[row,:]   (Q = cols 0..511 of QK, raw bf16)
__global__ __launch_bounds__(256) void gsum_kernel(const u16* __restrict__ QK,
                                                   const float* __restrict__ ssqQ,
                                                   float* __restrict__ g)
{
    __shared__ float gtile[4][512];
    const int lane = threadIdx.x & 63;
    const int wave = threadIdx.x >> 6;
    const int row0 = blockIdx.x * 128 + wave * 32;
    const int batch = row0 >> 12;
    const int d = lane * 8;
    float gacc[8] = {};
    for (int rr = 0; rr < 32; ++rr) {
        int row = row0 + rr;
        float s = rsqrtf(fmaxf(ssqQ[row], 1e-12f));
        u16x8 q = *(const u16x8*)(QK + (size_t)row * 1024 + d);
#pragma unroll
        for (int i = 0; i < 8; ++i) gacc[i] += s * bf2f(q[i]);
    }
#pragma unroll
    for (int i = 0; i < 8; ++i) gtile[wave][d + i] = gacc[i];
    __syncthreads();
    int c2 = threadIdx.x * 2;
    float s0 = gtile[0][c2]     + gtile[1][c2]     + gtile[2][c2]     + gtile[3][c2];
    float s1 = gtile[0][c2 + 1] + gtile[1][c2 + 1] + gtile[2][c2 + 1] + gtile[3][c2 + 1];
    atomicAdd(&g[batch * 512 + c2], s0);
    atomicAdd(&g[batch * 512 + c2 + 1], s1);
}

// BtP8[b][n][k] = bf16(g[b][k] * wp[k][n])  — folds the g scaling into per-batch weights.
__global__ __launch_bounds__(256) void scale_wp_kernel(const float* __restrict__ wp,
                                                       const float* __restrict__ g,
                                                       u16* __restrict__ BtP8)
{
    __shared__ u16 tile[32][34];
    const int b   = blockIdx.x >> 8;
    const int bid = blockIdx.x & 255;
    const int tk = bid & 15;
    const int tn = bid >> 4;
    const int c  = threadIdx.x & 31;
    const int r0 = threadIdx.x >> 5;
    const float* gb = g + b * 512;
#pragma unroll
    for (int i = 0; i < 4; ++i) {
        int r = r0 + i * 8;
        int k = tk * 32 + r;
        tile[r][c] = f2bf(gb[k] * wp[(size_t)k * 512 + tn * 32 + c]);
    }
    __syncthreads();
    u16* Bt = BtP8 + (size_t)b * 512 * 512;
#pragma unroll
    for (int i = 0; i < 4; ++i) {
        int r = r0 + i * 8;
        Bt[(size_t)(tn * 32 + r) * 512 + tk * 32 + c] = tile[c][r];
    }
}

// x (fp32) -> bf16
__global__ __launch_bounds__(256) void convert_x_kernel(const float* __restrict__ x, u16* __restrict__ xb)
{
    size_t i = ((size_t)blockIdx.x * 256 + threadIdx.x) * 4;
    float4 v = *(const float4*)(x + i);
    ushort4 o;
    o.x = f2bf(v.x); o.y = f2bf(v.y); o.z = f2bf(v.z); o.w = f2bf(v.w);
    *(ushort4*)(xb + i) = o;
}

// LDS-tiled transpose of three 512x512 fp32 weights (wq, wk, wf) -> bf16 B^T layout.
__global__ __launch_bounds__(256) void transpose3_kernel(
    const float* __restrict__ w0, const float* __restrict__ w1, const float* __restrict__ w2,
    u16* __restrict__ d0, u16* __restrict__ d1, u16* __restrict__ d2)
{
    __shared__ u16 tile[32][34];
    const int which = blockIdx.x >> 8;
    const float* W = (which == 0) ? w0 : (which == 1) ? w1 : w2;
    u16* Bt = (which == 0) ? d0 : (which == 1) ? d1 : d2;
    const int bid = blockIdx.x & 255;
    const int tk = bid & 15;
    const int tn = bid >> 4;
    const int c  = threadIdx.x & 31;
    const int r0 = threadIdx.x >> 5;
#pragma unroll
    for (int i = 0; i < 4; ++i) {
        int r = r0 + i * 8;
        tile[r][c] = f2bf(W[(size_t)(tk * 32 + r) * 512 + tn * 32 + c]);
    }
    __syncthreads();
#pragma unroll
    for (int i = 0; i < 4; ++i) {
        int r = r0 + i * 8;
        Bt[(size_t)(tn * 32 + r) * 512 + tk * 32 + c] = tile[c][r];
    }
}

// setup: biasQK = [bq|bk]; g = 0; ssq = 0   (one launch replaces bias_cat + 2 memsets)
__global__ __launch_bounds__(256) void setup_kernel(const float* __restrict__ bq,
                                                    const float* __restrict__ bk,
                                                    float* __restrict__ biasQK,
                                                    float* __restrict__ g,
                                                    float* __restrict__ ssq)
{
    int id = blockIdx.x * 256 + threadIdx.x;   // 0..65535
    if (id < 1024) biasQK[id] = (id < 512) ? bq[id] : bk[id - 512];
    if (id < 4096) g[id] = 0.f;
    ssq[id] = 0.f;                             // 2 x 32768
}

extern "C" void kernel_launch(void* const* d_in, const int* in_sizes, int n_in,
                              void* d_out, int out_size, void* d_ws, size_t ws_size,
                              hipStream_t stream)
{
    const float* x  = (const float*)d_in[0];
    const float* wq = (const float*)d_in[1];
    const float* bq = (const float*)d_in[2];
    const float* wk = (const float*)d_in[3];
    const float* bk = (const float*)d_in[4];
    const float* wp = (const float*)d_in[5];
    const float* bp = (const float*)d_in[6];
    const float* wf = (const float*)d_in[7];
    const float* bf = (const float*)d_in[8];
    // d_in[9] = w_g unused: softmax over a size-1 axis is identically 1.

    char* ws = (char*)d_ws;
    u16*   xb     = (u16*)(ws);                 // 32768 x 512 bf16 = 32 MiB
    u16*   T      = (u16*)(ws);                 // alias: xb dead after GEMM1
    u16*   QK     = (u16*)(ws + 33554432);      // 32768 x 1024 bf16 = 64 MiB
    u16*   Bt1    = (u16*)(ws + 100663296);     // 1024 x 512 bf16 = 1 MiB
    u16*   BtP8   = (u16*)(ws + 101711872);     // 8 x 512 x 512 bf16 = 4 MiB
    u16*   BtF    = (u16*)(ws + 105906176);     // 512 x 512 bf16
    float* biasQK = (float*)(ws + 106430464);   // 1024 fp32
    float* g      = (float*)(ws + 106434560);   // 8 x 512 fp32 = 16 KiB
    float* ssq    = (float*)(ws + 106450944);   // 2 x 32768 fp32 (Q norms, K norms)

    setup_kernel<<<256, 256, 0, stream>>>(bq, bk, biasQK, g, ssq);
    convert_x_kernel<<<16384, 256, 0, stream>>>(x, xb);
    transpose3_kernel<<<768, 256, 0, stream>>>(wq, wk, wf, Bt1, Bt1 + 512 * 512, BtF);

    // QK = x @ [wq|wk] + [bq|bk]  (bf16 out) + per-row ssq of Q,K halves     nwg = 2048
    gemm_bt<0><<<dim3(8, 256), 256, 0, stream>>>(
        xb, 512, Bt1, 0, biasQK, nullptr, 0, nullptr, nullptr, ssq, QK, nullptr, 1024, 512);
    // g[b,:] = sum_rows rsqrt(ssqQ[r]) * Q[r,:]
    gsum_kernel<<<256, 256, 0, stream>>>(QK, ssq, g);
    // fold g into per-batch wp:  BtP8[b] = (diag(g[b]) @ wp)^T
    scale_wp_kernel<<<2048, 256, 0, stream>>>(wp, g, BtP8);
    // T = rsk[row]*(Kraw @ (g*wp)) + bp + rsq[row]*Qraw   (bf16 out)         nwg = 1024
    gemm_bt<1><<<dim3(4, 256), 256, 0, stream>>>(
        QK + 512, 1024, BtP8, 512 * 512, bp, QK, 1024, ssq, ssq + 32768, nullptr, T, nullptr, 512, 512);
    // out = T @ wf + bf   (fp32 out)                                         nwg = 1024
    gemm_bt<2><<<dim3(4, 256), 256, 0, stream>>>(
        T, 512, BtF, 0, bf, nullptr, 0, nullptr, nullptr, nullptr, nullptr, (float*)d_out, 512, 512);
}

// Round 6
// 254.778 us; speedup vs baseline: 1.7693x; 1.0265x over previous
//
#include <hip/hip_runtime.h>
#include <stdint.h>

typedef __bf16 bf16x8 __attribute__((ext_vector_type(8)));
typedef float floatx4 __attribute__((ext_vector_type(4)));
typedef unsigned short u16;
typedef u16 u16x8 __attribute__((ext_vector_type(8)));

__device__ __forceinline__ float bf2f(u16 u) {
    union { uint32_t i; float f; } v; v.i = ((uint32_t)u) << 16; return v.f;
}
__device__ __forceinline__ u16 f2bf(float f) {
    union { float f; uint32_t i; } v; v.f = f;
    uint32_t r = v.i + 0x7fffu + ((v.i >> 16) & 1u);
    return (u16)(r >> 16);
}

// async global->LDS, 16B per lane. LDS dest wave-uniform base; HW adds lane*16.
__device__ __forceinline__ void gload_lds16(const u16* g, u16* l) {
    __builtin_amdgcn_global_load_lds(
        (const __attribute__((address_space(1))) void*)g,
        (__attribute__((address_space(3))) void*)l,
        16, 0, 0);
}

#define BK 64
// 256x256 tile, 8 waves (2M x 4N), depth-2 double-buffered counted-vmcnt pipeline (T3+T4).
// LDS: 2 bufs x (A 256x64 + B 256x64) bf16 = 128 KiB. 1 block/CU.
// Invariant: every wave issues exactly 8 gload_lds per K-tile, in uniform order, so
// "own vmcnt(8) wait + s_barrier" == "all waves' tile-t loads landed".
// Both-sides XOR swizzle (rule 21): linear gload_lds dest, pre-swizzled global k-offset,
// swizzled ds_read -> minimal (2-way) LDS bank aliasing, validated R2-R5.
// EPI=0: bf16 out + per-row output ssq -> ssq_out[(col0>>9)*Mtot + row]    (GEMM1)
// EPI=1: bf16 out, acc *= rsqrt(ssq_row[row]), += rsqrt(ssq_add[row])*addsrc (GEMM2)
// EPI=2: fp32 out, plain bias                                               (GEMM3)
template<int EPI>
__global__ __launch_bounds__(512, 2) void gemm_bt(
    const u16* __restrict__ A, int lda,
    const u16* __restrict__ Bt, long bstride,
    const float* __restrict__ bias,
    const u16* __restrict__ addsrc, int ldadd,
    const float* __restrict__ ssq_add,
    const float* __restrict__ ssq_row,
    float* __restrict__ ssq_out,
    u16* __restrict__ C16, float* __restrict__ C32, int ldc,
    int K)
{
    __shared__ __attribute__((aligned(16))) u16 lds[2 * 32768];  // 128 KiB
    const int tid  = threadIdx.x;
    const int wave = tid >> 6;
    const int lane = tid & 63;
    const int quad = lane >> 4;
    const int l16  = lane & 15;
    const int wm = wave >> 2, wn = wave & 3;   // 2 x 4 wave grid

    // XCD-aware chunked swizzle (all launches have nwg % 8 == 0)
    const int gx   = gridDim.x;
    const int nwg  = gx * gridDim.y;
    const int wgid = blockIdx.y * gx + blockIdx.x;
    const int cpx  = nwg >> 3;
    const int swz  = (wgid & 7) * cpx + (wgid >> 3);
    const int row0 = (swz / gx) * 256;
    const int col0 = (swz % gx) * 256;
    const int batch = row0 >> 12;
    const int Mtot  = gridDim.y * 256;

    floatx4 acc[8][4] = {};

    // staging: chunk cc = wave*4+c covers 8 rows; lane l -> row cc*8+(l>>3),
    // k-offset pre-swizzled by row&7 so linear LDS dest + swizzled ds_read agree.
    const int rsub = lane >> 3;
    const int ksub = ((lane & 7) ^ rsub) << 3;
    const u16* aptr[4]; const u16* bptr[4];
    const u16* Bb = Bt + (size_t)batch * bstride;
#pragma unroll
    for (int c = 0; c < 4; ++c) {
        const int cc = wave * 4 + c;
        aptr[c] = A  + (size_t)(row0 + cc * 8 + rsub) * lda + ksub;
        bptr[c] = Bb + (size_t)(col0 + cc * 8 + rsub) * K   + ksub;
    }

    const int NT = K >> 6;   // 8 for all our calls (>= 2 required)

#define STAGE(T, B)                                                        \
    {                                                                      \
        u16* sA_ = &lds[(B) * 32768];                                      \
        u16* sB_ = sA_ + 16384;                                            \
        const int kt_ = (T) * BK;                                          \
        _Pragma("unroll")                                                  \
        for (int c = 0; c < 4; ++c) {                                      \
            const int cc = wave * 4 + c;                                   \
            gload_lds16(aptr[c] + kt_, &sA_[cc * 512]);                    \
            gload_lds16(bptr[c] + kt_, &sB_[cc * 512]);                    \
        }                                                                  \
    }

    // prologue: tiles 0,1 into bufs 0,1  (16 loads/wave in flight)
    STAGE(0, 0);
    STAGE(1, 1);

    for (int t = 0; t < NT; ++t) {
        // leading edge: own tile-t loads landed (8 newer stay in flight), then collective
        if (t + 1 < NT) asm volatile("s_waitcnt vmcnt(8)" ::: "memory");
        else            asm volatile("s_waitcnt vmcnt(0)" ::: "memory");
        __builtin_amdgcn_s_barrier();
        __builtin_amdgcn_sched_barrier(0);

        const u16* sA = &lds[(t & 1) * 32768];
        const u16* sB = sA + 16384;
#pragma unroll
        for (int ks = 0; ks < 2; ++ks) {
            const int cidx = ks * 4 + quad;
            const int pgo = ((cidx ^ (l16 & 7)) << 3);
            bf16x8 bfr[4];
#pragma unroll
            for (int n = 0; n < 4; ++n)
                bfr[n] = *(const bf16x8*)&sB[(wn * 64 + n * 16 + l16) * BK + pgo];
            __builtin_amdgcn_s_setprio(1);
#pragma unroll
            for (int m = 0; m < 8; ++m) {
                bf16x8 af = *(const bf16x8*)&sA[(wm * 128 + m * 16 + l16) * BK + pgo];
#pragma unroll
                for (int n = 0; n < 4; ++n)
                    acc[m][n] = __builtin_amdgcn_mfma_f32_16x16x32_bf16(af, bfr[n], acc[m][n], 0, 0, 0);
            }
            __builtin_amdgcn_s_setprio(0);
        }

        // trailing edge: pin compute (and its lgkmcnt) inside the phase, then collective,
        // then overwrite buf[t&1] with tile t+2 (has ~2 K-tiles of compute to land)
        __builtin_amdgcn_sched_barrier(0);
        asm volatile("" ::: "memory");
        __builtin_amdgcn_s_barrier();
        asm volatile("" ::: "memory");
        if (t + 2 < NT) STAGE(t + 2, t & 1);
    }
#undef STAGE

    // ---------------- epilogue. C/D layout: col=lane&15, row=quad*4+reg (validated) ----
    if constexpr (EPI == 0 || EPI == 1) {
        u16* til = lds;  // [128][264] u16 = 67584 B, aliases staging LDS (safe: loop drained)
#pragma unroll
        for (int h = 0; h < 2; ++h) {
            __syncthreads();
            if (wm == h) {
                float bv[4];
#pragma unroll
                for (int n = 0; n < 4; ++n) bv[n] = bias[col0 + wn * 64 + n * 16 + l16];
#pragma unroll
                for (int m = 0; m < 8; ++m) {
                    int rowl = m * 16 + quad * 4;
                    int rowb = row0 + h * 128 + rowl;
                    float rsr4[4], rsa4[4];
                    if constexpr (EPI == 1) {
                        float4 rr = *(const float4*)&ssq_row[rowb];
                        float4 ra = *(const float4*)&ssq_add[rowb];
                        rsr4[0] = rsqrtf(fmaxf(rr.x, 1e-12f));
                        rsr4[1] = rsqrtf(fmaxf(rr.y, 1e-12f));
                        rsr4[2] = rsqrtf(fmaxf(rr.z, 1e-12f));
                        rsr4[3] = rsqrtf(fmaxf(rr.w, 1e-12f));
                        rsa4[0] = rsqrtf(fmaxf(ra.x, 1e-12f));
                        rsa4[1] = rsqrtf(fmaxf(ra.y, 1e-12f));
                        rsa4[2] = rsqrtf(fmaxf(ra.z, 1e-12f));
                        rsa4[3] = rsqrtf(fmaxf(ra.w, 1e-12f));
                    }
#pragma unroll
                    for (int n = 0; n < 4; ++n) {
                        int tcol = wn * 64 + n * 16 + l16;
#pragma unroll
                        for (int t = 0; t < 4; ++t) {
                            float v;
                            if constexpr (EPI == 1) {
                                v = acc[m][n][t] * rsr4[t] + bv[n]
                                  + bf2f(addsrc[(size_t)(rowb + t) * ldadd + col0 + tcol]) * rsa4[t];
                            } else {
                                v = acc[m][n][t] + bv[n];
                            }
                            til[(rowl + t) * 264 + tcol] = f2bf(v);
                        }
                    }
                }
            }
            __syncthreads();
            float ssl[8];
#pragma unroll
            for (int c = 0; c < 8; ++c) {
                int r  = c * 16 + (tid >> 5);
                int cu = (tid & 31) * 8;
                ushort4 lo = *(const ushort4*)&til[r * 264 + cu];
                ushort4 hi = *(const ushort4*)&til[r * 264 + cu + 4];
                u16x8 o;
                o[0] = lo.x; o[1] = lo.y; o[2] = lo.z; o[3] = lo.w;
                o[4] = hi.x; o[5] = hi.y; o[6] = hi.z; o[7] = hi.w;
                *(u16x8*)&C16[(size_t)(row0 + h * 128 + r) * ldc + col0 + cu] = o;
                if constexpr (EPI == 0) {
                    float ss = 0.f;
#pragma unroll
                    for (int q2 = 0; q2 < 8; ++q2) { float f = bf2f(o[q2]); ss += f * f; }
                    ssl[c] = ss;
                }
            }
            if constexpr (EPI == 0) {
                // 8 independent 32-lane reduce chains (row shared by a 32-lane half-wave)
                float* so = ssq_out + (size_t)(col0 >> 9) * Mtot + row0 + h * 128;
#pragma unroll
                for (int c = 0; c < 8; ++c) {
                    float s = ssl[c];
                    s += __shfl_xor(s, 1);
                    s += __shfl_xor(s, 2);
                    s += __shfl_xor(s, 4);
                    s += __shfl_xor(s, 8);
                    s += __shfl_xor(s, 16);
                    if ((lane & 31) == 0) atomicAdd(&so[c * 16 + (tid >> 5)], s);
                }
            }
        }
    } else {
        // EPI=2: fp32 out, 4 passes of 64 rows through a [64][264] f32 tile (67584 B)
        float* ftile = (float*)lds;
#pragma unroll
        for (int p = 0; p < 4; ++p) {
            __syncthreads();
            if (wm == (p >> 1)) {
                float bv[4];
#pragma unroll
                for (int n = 0; n < 4; ++n) bv[n] = bias[col0 + wn * 64 + n * 16 + l16];
#pragma unroll
                for (int mi = 0; mi < 4; ++mi) {
                    int m = (p & 1) * 4 + mi;
                    int rowl = mi * 16 + quad * 4;
#pragma unroll
                    for (int n = 0; n < 4; ++n) {
                        int tcol = wn * 64 + n * 16 + l16;
#pragma unroll
                        for (int t = 0; t < 4; ++t)
                            ftile[(rowl + t) * 264 + tcol] = acc[m][n][t] + bv[n];
                    }
                }
            }
            __syncthreads();
#pragma unroll
            for (int c = 0; c < 8; ++c) {
                int r  = c * 8 + wave;
                int cu = lane * 4;
                float4 v = *(const float4*)&ftile[r * 264 + cu];
                *(float4*)&C32[(size_t)(row0 + p * 64 + r) * ldc + col0 + cu] = v;
            }
        }
    }
}

// g[b,:] += sum_rows rsqrt(ssqQ[row]) * Q[row,:]   (Q = cols 0..511 of QK, raw bf16)
__global__ __launch_bounds__(256) void gsum_kernel(const u16* __restrict__ QK,
                                                   const float* __restrict__ ssqQ,
                                                   float* __restrict__ g)
{
    __shared__ float gtile[4][512];
    const int lane = threadIdx.x & 63;
    const int wave = threadIdx.x >> 6;
    const int row0 = blockIdx.x * 128 + wave * 32;
    const int batch = row0 >> 12;
    const int d = lane * 8;
    float gacc[8] = {};
    for (int rr = 0; rr < 32; ++rr) {
        int row = row0 + rr;
        float s = rsqrtf(fmaxf(ssqQ[row], 1e-12f));
        u16x8 q = *(const u16x8*)(QK + (size_t)row * 1024 + d);
#pragma unroll
        for (int i = 0; i < 8; ++i) gacc[i] += s * bf2f(q[i]);
    }
#pragma unroll
    for (int i = 0; i < 8; ++i) gtile[wave][d + i] = gacc[i];
    __syncthreads();
    int c2 = threadIdx.x * 2;
    float s0 = gtile[0][c2]     + gtile[1][c2]     + gtile[2][c2]     + gtile[3][c2];
    float s1 = gtile[0][c2 + 1] + gtile[1][c2 + 1] + gtile[2][c2 + 1] + gtile[3][c2 + 1];
    atomicAdd(&g[batch * 512 + c2], s0);
    atomicAdd(&g[batch * 512 + c2 + 1], s1);
}

// BtP8[b][n][k] = bf16(g[b][k] * wp[k][n])  — folds the g scaling into per-batch weights.
__global__ __launch_bounds__(256) void scale_wp_kernel(const float* __restrict__ wp,
                                                       const float* __restrict__ g,
                                                       u16* __restrict__ BtP8)
{
    __shared__ u16 tile[32][34];
    const int b   = blockIdx.x >> 8;
    const int bid = blockIdx.x & 255;
    const int tk = bid & 15;
    const int tn = bid >> 4;
    const int c  = threadIdx.x & 31;
    const int r0 = threadIdx.x >> 5;
    const float* gb = g + b * 512;
#pragma unroll
    for (int i = 0; i < 4; ++i) {
        int r = r0 + i * 8;
        int k = tk * 32 + r;
        tile[r][c] = f2bf(gb[k] * wp[(size_t)k * 512 + tn * 32 + c]);
    }
    __syncthreads();
    u16* Bt = BtP8 + (size_t)b * 512 * 512;
#pragma unroll
    for (int i = 0; i < 4; ++i) {
        int r = r0 + i * 8;
        Bt[(size_t)(tn * 32 + r) * 512 + tk * 32 + c] = tile[c][r];
    }
}

// x (fp32) -> bf16
__global__ __launch_bounds__(256) void convert_x_kernel(const float* __restrict__ x, u16* __restrict__ xb)
{
    size_t i = ((size_t)blockIdx.x * 256 + threadIdx.x) * 4;
    float4 v = *(const float4*)(x + i);
    ushort4 o;
    o.x = f2bf(v.x); o.y = f2bf(v.y); o.z = f2bf(v.z); o.w = f2bf(v.w);
    *(ushort4*)(xb + i) = o;
}

// LDS-tiled transpose of three 512x512 fp32 weights (wq, wk, wf) -> bf16 B^T layout.
__global__ __launch_bounds__(256) void transpose3_kernel(
    const float* __restrict__ w0, const float* __restrict__ w1, const float* __restrict__ w2,
    u16* __restrict__ d0, u16* __restrict__ d1, u16* __restrict__ d2)
{
    __shared__ u16 tile[32][34];
    const int which = blockIdx.x >> 8;
    const float* W = (which == 0) ? w0 : (which == 1) ? w1 : w2;
    u16* Bt = (which == 0) ? d0 : (which == 1) ? d1 : d2;
    const int bid = blockIdx.x & 255;
    const int tk = bid & 15;
    const int tn = bid >> 4;
    const int c  = threadIdx.x & 31;
    const int r0 = threadIdx.x >> 5;
#pragma unroll
    for (int i = 0; i < 4; ++i) {
        int r = r0 + i * 8;
        tile[r][c] = f2bf(W[(size_t)(tk * 32 + r) * 512 + tn * 32 + c]);
    }
    __syncthreads();
#pragma unroll
    for (int i = 0; i < 4; ++i) {
        int r = r0 + i * 8;
        Bt[(size_t)(tn * 32 + r) * 512 + tk * 32 + c] = tile[c][r];
    }
}

// setup: biasQK = [bq|bk]; g = 0; ssq = 0
__global__ __launch_bounds__(256) void setup_kernel(const float* __restrict__ bq,
                                                    const float* __restrict__ bk,
                                                    float* __restrict__ biasQK,
                                                    float* __restrict__ g,
                                                    float* __restrict__ ssq)
{
    int id = blockIdx.x * 256 + threadIdx.x;   // 0..65535
    if (id < 1024) biasQK[id] = (id < 512) ? bq[id] : bk[id - 512];
    if (id < 4096) g[id] = 0.f;
    ssq[id] = 0.f;                             // 2 x 32768
}

extern "C" void kernel_launch(void* const* d_in, const int* in_sizes, int n_in,
                              void* d_out, int out_size, void* d_ws, size_t ws_size,
                              hipStream_t stream)
{
    const float* x  = (const float*)d_in[0];
    const float* wq = (const float*)d_in[1];
    const float* bq = (const float*)d_in[2];
    const float* wk = (const float*)d_in[3];
    const float* bk = (const float*)d_in[4];
    const float* wp = (const float*)d_in[5];
    const float* bp = (const float*)d_in[6];
    const float* wf = (const float*)d_in[7];
    const float* bf = (const float*)d_in[8];
    // d_in[9] = w_g unused: softmax over a size-1 axis is identically 1.

    char* ws = (char*)d_ws;
    u16*   xb     = (u16*)(ws);                 // 32768 x 512 bf16 = 32 MiB
    u16*   T      = (u16*)(ws);                 // alias: xb dead after GEMM1
    u16*   QK     = (u16*)(ws + 33554432);      // 32768 x 1024 bf16 = 64 MiB
    u16*   Bt1    = (u16*)(ws + 100663296);     // 1024 x 512 bf16 = 1 MiB
    u16*   BtP8   = (u16*)(ws + 101711872);     // 8 x 512 x 512 bf16 = 4 MiB
    u16*   BtF    = (u16*)(ws + 105906176);     // 512 x 512 bf16
    float* biasQK = (float*)(ws + 106430464);   // 1024 fp32
    float* g      = (float*)(ws + 106434560);   // 8 x 512 fp32
    float* ssq    = (float*)(ws + 106450944);   // 2 x 32768 fp32 (Q norms, K norms)

    setup_kernel<<<256, 256, 0, stream>>>(bq, bk, biasQK, g, ssq);
    convert_x_kernel<<<16384, 256, 0, stream>>>(x, xb);
    transpose3_kernel<<<768, 256, 0, stream>>>(wq, wk, wf, Bt1, Bt1 + 512 * 512, BtF);

    // QK = x @ [wq|wk] + [bq|bk]  (bf16 out) + per-row ssq of Q,K halves   nwg = 512
    gemm_bt<0><<<dim3(4, 128), 512, 0, stream>>>(
        xb, 512, Bt1, 0, biasQK, nullptr, 0, nullptr, nullptr, ssq, QK, nullptr, 1024, 512);
    // g[b,:] = sum_rows rsqrt(ssqQ[r]) * Q[r,:]
    gsum_kernel<<<256, 256, 0, stream>>>(QK, ssq, g);
    // fold g into per-batch wp:  BtP8[b] = (diag(g[b]) @ wp)^T
    scale_wp_kernel<<<2048, 256, 0, stream>>>(wp, g, BtP8);
    // T = rsk[row]*(Kraw @ (g*wp)) + bp + rsq[row]*Qraw   (bf16 out)       nwg = 256
    gemm_bt<1><<<dim3(2, 128), 512, 0, stream>>>(
        QK + 512, 1024, BtP8, 512 * 512, bp, QK, 1024, ssq, ssq + 32768, nullptr, T, nullptr, 512, 512);
    // out = T @ wf + bf   (fp32 out)                                       nwg = 256
    gemm_bt<2><<<dim3(2, 128), 512, 0, stream>>>(
        T, 512, BtF, 0, bf, nullptr, 0, nullptr, nullptr, nullptr, nullptr, (float*)d_out, 512, 512);
}